// Round 4
// baseline (15.587 us; speedup 1.0000x reference)
//
#include <hip/hip_runtime.h>
#include <hip/hip_bf16.h>

// KAN layer as GEMM: y[b,o] = sum_kk F[b][kk] * Wt[o][kk],  KK = 2304.
// PLANAR K layout: kk = n*256 + d  (n = feature 0..8: 8 B-spline funcs + silu).
// A consistent permutation of K leaves the sum unchanged but makes every
// prep store coalesced (adjacent d -> adjacent 2B addresses).
// Uniform cubic B-spline (all grid rows identical): closed form.

#define KK 2304

typedef __attribute__((ext_vector_type(8))) short bf16x8;
typedef __attribute__((ext_vector_type(4))) float f32x4;

// ---------- Phase 1: build F (blocks 0..255, b) and Wt (blocks 256..511, o)
__global__ __launch_bounds__(256) void kan_prep(
        const float* __restrict__ x, const float* __restrict__ grid,
        const float* __restrict__ coef, const float* __restrict__ sb,
        const float* __restrict__ ss,
        __hip_bfloat16* __restrict__ F, __hip_bfloat16* __restrict__ Wt) {
    int d = threadIdx.x;
    if (blockIdx.x < 256) {
        int b = blockIdx.x;
        float xv = x[b * 256 + d];                  // coalesced
        float gl = grid[0], gr = grid[5];           // uniform -> s_load
        float h = (gr - gl) * 0.2f;
        float g0 = gl - 3.f * h;
        float tt = (xv - g0) / h;
        float fi = floorf(tt);
        int   i  = (int)fi;
        float u  = tt - fi;
        float valid = (tt >= 0.f && tt < 11.f) ? 1.f : 0.f;
        float u2 = u * u, u3 = u2 * u, um = 1.f - u;
        const float k6 = 1.f / 6.f;
        float b3 = u3 * k6 * valid;                               // N_i
        float b2 = (-3.f*u3 + 3.f*u2 + 3.f*u + 1.f) * k6 * valid; // N_{i-1}
        float b1 = (3.f*u3 - 6.f*u2 + 4.f) * k6 * valid;          // N_{i-2}
        float b0 = um * um * um * k6 * valid;                     // N_{i-3}
        __hip_bfloat16* dst = F + (size_t)b * KK + d;
#pragma unroll
        for (int n = 0; n < 8; ++n) {               // plane-n store, coalesced in d
            int r = i - n;
            float Nv = (r == 0) ? b3 : (r == 1) ? b2 : (r == 2) ? b1
                     : (r == 3) ? b0 : 0.f;
            dst[n * 256] = __float2bfloat16(Nv);
        }
        dst[8 * 256] = __float2bfloat16(xv / (1.f + __expf(-xv)));  // silu plane
    } else {
        int o = blockIdx.x - 256;
        int s = o * 256 + d;
        float4 c0 = *(const float4*)(coef + (size_t)s * 8);       // coalesced
        float4 c1 = *(const float4*)(coef + (size_t)s * 8 + 4);
        float vb = sb[s], vs = ss[s];
        __hip_bfloat16* dst = Wt + (size_t)o * KK + d;
        dst[0 * 256] = __float2bfloat16(vs * c0.x);
        dst[1 * 256] = __float2bfloat16(vs * c0.y);
        dst[2 * 256] = __float2bfloat16(vs * c0.z);
        dst[3 * 256] = __float2bfloat16(vs * c0.w);
        dst[4 * 256] = __float2bfloat16(vs * c1.x);
        dst[5 * 256] = __float2bfloat16(vs * c1.y);
        dst[6 * 256] = __float2bfloat16(vs * c1.z);
        dst[7 * 256] = __float2bfloat16(vs * c1.w);
        dst[8 * 256] = __float2bfloat16(vb);
    }
}

// ---------- Phase 2: 256 blocks x 512 threads; 16x16 output tile, K=2304.
// 8 waves split the 72 k-steps (9 each) -> 2 waves/SIMD for latency overlap.
__global__ __launch_bounds__(512) void kan_gemm(
        const __hip_bfloat16* __restrict__ F, const __hip_bfloat16* __restrict__ Wt,
        float* __restrict__ out) {
    int tr   = blockIdx.x & 15;          // b-tile
    int tc   = blockIdx.x >> 4;          // o-tile
    int lane = threadIdx.x & 63;
    int wave = threadIdx.x >> 6;         // 0..7
    int r16  = lane & 15;
    int kg   = lane >> 4;

    const __hip_bfloat16* ap = F  + (size_t)(tr * 16 + r16) * KK + kg * 8;
    const __hip_bfloat16* bp = Wt + (size_t)(tc * 16 + r16) * KK + kg * 8;

    f32x4 acc = {0.f, 0.f, 0.f, 0.f};
    int s0 = wave * 9;                   // 9 k-steps of 32 per wave
#pragma unroll
    for (int s = 0; s < 9; ++s) {
        bf16x8 a = *reinterpret_cast<const bf16x8*>(ap + (s0 + s) * 32);
        bf16x8 b = *reinterpret_cast<const bf16x8*>(bp + (s0 + s) * 32);
        acc = __builtin_amdgcn_mfma_f32_16x16x32_bf16(a, b, acc, 0, 0, 0);
    }

    // All 8 waves dump partials; 256 threads re-own (lane,j) pairs and reduce
    // with consecutive-dword (conflict-free) LDS reads.
    __shared__ float red[8][64][4];
#pragma unroll
    for (int j = 0; j < 4; ++j) red[wave][lane][j] = acc[j];
    __syncthreads();
    int t = threadIdx.x;
    if (t < 256) {
        int l2 = t >> 2, j2 = t & 3;
        float v = 0.f;
#pragma unroll
        for (int w = 0; w < 8; ++w) v += red[w][l2][j2];
        // C layout: col = lane&15, row = (lane>>4)*4 + j   [m89-verified]
        out[(size_t)(tr * 16 + (l2 >> 4) * 4 + j2) * 256 + tc * 16 + (l2 & 15)] = v;
    }
}

extern "C" void kernel_launch(void* const* d_in, const int* in_sizes, int n_in,
                              void* d_out, int out_size, void* d_ws, size_t ws_size,
                              hipStream_t stream) {
    const float* x    = (const float*)d_in[0];   // [256,256]
    const float* grid = (const float*)d_in[1];   // [65536,6] (rows identical)
    const float* coef = (const float*)d_in[2];   // [65536,8]
    const float* sb   = (const float*)d_in[3];   // [65536]
    const float* ss   = (const float*)d_in[4];   // [65536]
    float* out = (float*)d_out;                  // [256,256] f32

    char* ws = (char*)d_ws;
    __hip_bfloat16* F  = (__hip_bfloat16*)ws;                   // 1.125 MB
    __hip_bfloat16* Wt = (__hip_bfloat16*)(ws + (2u << 20));    // 1.125 MB

    kan_prep<<<512, 256, 0, stream>>>(x, grid, coef, sb, ss, F, Wt);
    kan_gemm<<<256, 512, 0, stream>>>(F, Wt, out);
}